// Round 3
// baseline (333.960 us; speedup 1.0000x reference)
//
#include <hip/hip_runtime.h>
#include <stdint.h>

// Problem dims (fixed by setup_inputs)
#define M_TOTAL 2048     // B (feats rows)
#define N_TOTAL 16384    // Bs*TOPK (support rows)
#define K_TOTAL 2048     // C
#define NPARTS  256      // 64 n-tiles * 4 n-waves
#define NT      (K_TOTAL / 128)   // 16 K-tiles

// Uniform MX scale: stored_fp8 = value * 2^9, HW dequant scale = 2^-9 per operand.
#define SCALE_E8M0 0x76767676
#define SCALE_F 512.0f

typedef __attribute__((ext_vector_type(4))) int   int4v;    // 16B (one ds_read_b128)
typedef __attribute__((ext_vector_type(8))) int   int8v;    // 32B fp8 MFMA A/B frag
typedef __attribute__((ext_vector_type(4))) float floatx4;  // MFMA C/D frag

// ---------------------------------------------------------------- fp32 -> fp8 e4m3 (scaled)
__device__ __forceinline__ uint32_t pack8(float4 v) {
    int p = __builtin_amdgcn_cvt_pk_fp8_f32(v.x * SCALE_F, v.y * SCALE_F, 0, 0);
    p = __builtin_amdgcn_cvt_pk_fp8_f32(v.z * SCALE_F, v.w * SCALE_F, p, 1);
    return (uint32_t)p;
}

__device__ __forceinline__ void cvt_loop16(const float4* __restrict__ src,
                                           uint4* __restrict__ dst,
                                           int i, int stride, int n16) {
    for (; i < n16; i += stride) {
        const float4* p = src + (size_t)i * 4;
        uint4 o;
        o.x = pack8(p[0]);
        o.y = pack8(p[1]);
        o.z = pack8(p[2]);
        o.w = pack8(p[3]);
        dst[i] = o;
    }
}

__global__ __launch_bounds__(256) void cvt_fp8_all(
        const float4* __restrict__ a, const float4* __restrict__ b,
        uint4* __restrict__ oa, uint4* __restrict__ ob) {
    if (blockIdx.x < 512)
        cvt_loop16(a, oa, blockIdx.x * 256 + threadIdx.x, 512 * 256,
                   M_TOTAL * K_TOTAL / 16);
    else
        cvt_loop16(b, ob, (blockIdx.x - 512) * 256 + threadIdx.x, 2048 * 256,
                   N_TOTAL * K_TOTAL / 16);
}

// ---------------------------------------------------------------- GEMM + fused epilogue
__device__ __forceinline__ void load16(const void* g, void* l) {
    __builtin_amdgcn_global_load_lds(
        (const __attribute__((address_space(1))) void*)g,
        (__attribute__((address_space(3))) void*)l, 16, 0, 0);
}

__device__ __forceinline__ int8v frag8(const char* lo_p, const char* hi_p) {
    int4v lo = *(const int4v*)lo_p;
    int4v hi = *(const int4v*)hi_p;
    return (int8v){lo.x, lo.y, lo.z, lo.w, hi.x, hi.y, hi.z, hi.w};
}

// ===== 256x256 / 8 waves / dbuf LDS, now with FINE 4-phase-per-tile interleave.
// Round-1 (coarse 2-phase counted-vmcnt) measured 101us, MfmaUtil 28%: with
// monolithic read-then-MFMA sections, LDS (~2260cy/tile/CU) and MFMA
// (~2211cy/tile/CU) serialize instead of overlapping. This version pipelines
// ds_reads ONE PHASE AHEAD with counted lgkmcnt so both pipes run concurrently:
//   p0: stage ALL 8 gloads (tile t+1 -> other buf) + read A frags 0..3;
//       BAR; lgkm(4) [B-pre + a0,a1 landed; a2,a3 fly]; MFMA rows 0,1
//   p1: read A 4,5; BAR; lgkm(4); MFMA rows 2,3
//   p2: read A 6,7; BAR; lgkm(4); MFMA rows 4,5; vmcnt(0) [stages landed,
//       ~3 phases of cover >= HBM latency]; BAR  -> publishes buf t+1
//   p3: read next tile's B frags (8, from just-published buf); lgkm(8)
//       [a6,a7 landed; B' flies across the tile boundary]; MFMA rows 6,7; BAR
// Hazards: stages at p0 target the buffer whose last readers (tile t-1, A 6,7)
// retired before the previous end-BAR; B' pre-reads follow the publish BAR.
// All barriers uniform. K-loop unrolled x2 with B-register role swap (bv/bn).
__global__ __launch_bounds__(512, 2) void gemm_lp(
        const char* __restrict__ Af8, const char* __restrict__ Bf8,
        const int* __restrict__ labels, const int* __restrict__ labels_s,
        float* __restrict__ pminp, float* __restrict__ psump) {
    __shared__ __align__(16) char smA[2][256][128];   // 64 KiB
    __shared__ __align__(16) char smB[2][256][128];   // 64 KiB
    __shared__ int lab_m[256];
    __shared__ int lab_n[256];

    const int t    = threadIdx.x;
    const int lane = t & 63;
    const int wave = t >> 6;      // 0..7
    const int wm   = wave >> 2;   // row half   (0..1) -> 128 rows
    const int wn   = wave & 3;    // col quarter(0..3) -> 64 cols
    const int m0   = blockIdx.y * 256;
    const int n0   = blockIdx.x * 256;

    if (t < 256) lab_m[t] = labels[m0 + t];
    else         lab_n[t - 256] = labels_s[n0 + t - 256];

    // staging geometry: round j (0..3) covers rows j*64 + (t>>3); phys chunk t&7
    // -> global k-chunk q = (t&7) ^ ((t>>3)&7)  (row&7 is j-independent).
    const int rq = t >> 3;                                  // 0..63
    const int qt = (t & 7) ^ ((t >> 3) & 7);
    const char* aG = Af8 + (long)(m0 + rq) * K_TOTAL + qt * 16;
    const char* bG = Bf8 + (long)(n0 + rq) * K_TOTAL + qt * 16;
    const int ldst = wave * 1024;            // wave-uniform LDS base; HW adds lane*16B

#define STAGE_A(T, J) load16(aG + (T) * 128 + (J) * 64 * K_TOTAL, \
                             &smA[(T) & 1][(J) * 64][0] + ldst)
#define STAGE_B(T, J) load16(bG + (T) * 128 + (J) * 64 * K_TOTAL, \
                             &smB[(T) & 1][(J) * 64][0] + ldst)

    // Fragment bases: row R = base + lcol (+ mi*16 via 2048B immediates),
    // k-chunks {2q, 2q+1} at phys (k ^ (lcol&7)).
    const int quad = lane >> 4;
    const int lcol = lane & 15;
    const int plo = ((2 * quad)     ^ (lcol & 7)) << 4;
    const int phi = ((2 * quad + 1) ^ (lcol & 7)) << 4;
    const char* aF = &smA[0][wm * 128 + lcol][0];
    const char* bF = &smB[0][wn * 64  + lcol][0];

#define RD(P) frag8((P) + plo, (P) + phi)

    floatx4 acc[8][4];
#pragma unroll
    for (int mi = 0; mi < 8; ++mi)
#pragma unroll
        for (int ni = 0; ni < 4; ++ni)
            acc[mi][ni] = (floatx4){0.f, 0.f, 0.f, 0.f};

    int8v bv[4], bn[4];

#define MFMA_PAIR(R, AV0, AV1, BARR)                                           \
    do {                                                                       \
        _Pragma("unroll")                                                      \
        for (int ni = 0; ni < 4; ++ni) {                                       \
            acc[R][ni] = __builtin_amdgcn_mfma_scale_f32_16x16x128_f8f6f4(     \
                AV0, BARR[ni], acc[R][ni], 0, 0, 0, SCALE_E8M0, 0, SCALE_E8M0);\
            acc[R + 1][ni] = __builtin_amdgcn_mfma_scale_f32_16x16x128_f8f6f4( \
                AV1, BARR[ni], acc[R + 1][ni], 0, 0, 0, SCALE_E8M0, 0,         \
                SCALE_E8M0);                                                   \
        }                                                                      \
    } while (0)

#define TILE(KT, BC, BN)                                                       \
    do {                                                                       \
        const int cur_ = (KT) & 1;                                             \
        const char* aB_ = aF + cur_ * 32768;                                   \
        const char* bN_ = bF + (cur_ ^ 1) * 32768;                             \
        /* ---- p0: stage next tile + read A frags 0..3 */                     \
        if ((KT) + 1 < NT) {                                                   \
            _Pragma("unroll")                                                  \
            for (int j = 0; j < 4; ++j) {                                      \
                STAGE_A((KT) + 1, j);                                          \
                STAGE_B((KT) + 1, j);                                          \
            }                                                                  \
        }                                                                      \
        int8v a0_ = RD(aB_ + 0 * 2048), a1_ = RD(aB_ + 1 * 2048);              \
        int8v a2_ = RD(aB_ + 2 * 2048), a3_ = RD(aB_ + 3 * 2048);              \
        __builtin_amdgcn_s_barrier();                                          \
        asm volatile("s_waitcnt lgkmcnt(4)" ::: "memory");                     \
        __builtin_amdgcn_sched_barrier(0);                                     \
        __builtin_amdgcn_s_setprio(1);                                         \
        MFMA_PAIR(0, a0_, a1_, BC);                                            \
        __builtin_amdgcn_s_setprio(0);                                         \
        __builtin_amdgcn_s_barrier();                                          \
        /* ---- p1 */                                                          \
        int8v a4_ = RD(aB_ + 4 * 2048), a5_ = RD(aB_ + 5 * 2048);              \
        __builtin_amdgcn_s_barrier();                                          \
        asm volatile("s_waitcnt lgkmcnt(4)" ::: "memory");                     \
        __builtin_amdgcn_sched_barrier(0);                                     \
        __builtin_amdgcn_s_setprio(1);                                         \
        MFMA_PAIR(2, a2_, a3_, BC);                                            \
        __builtin_amdgcn_s_setprio(0);                                         \
        __builtin_amdgcn_s_barrier();                                          \
        /* ---- p2 */                                                          \
        int8v a6_ = RD(aB_ + 6 * 2048), a7_ = RD(aB_ + 7 * 2048);              \
        __builtin_amdgcn_s_barrier();                                          \
        asm volatile("s_waitcnt lgkmcnt(4)" ::: "memory");                     \
        __builtin_amdgcn_sched_barrier(0);                                     \
        __builtin_amdgcn_s_setprio(1);                                         \
        MFMA_PAIR(4, a4_, a5_, BC);                                            \
        __builtin_amdgcn_s_setprio(0);                                         \
        asm volatile("s_waitcnt vmcnt(0)" ::: "memory");                       \
        __builtin_amdgcn_s_barrier(); /* publish buf (KT+1)&1 */               \
        /* ---- p3: pre-read next tile's B under our MFMAs */                  \
        _Pragma("unroll")                                                      \
        for (int ni = 0; ni < 4; ++ni) BN[ni] = RD(bN_ + ni * 2048);           \
        asm volatile("s_waitcnt lgkmcnt(8)" ::: "memory");                     \
        __builtin_amdgcn_sched_barrier(0);                                     \
        __builtin_amdgcn_s_setprio(1);                                         \
        MFMA_PAIR(6, a6_, a7_, BC);                                            \
        __builtin_amdgcn_s_setprio(0);                                         \
        __builtin_amdgcn_s_barrier(); /* end: all reads of buf KT&1 retired */ \
    } while (0)

    // Prologue: stage tile 0, publish, pre-read its B fragments.
#pragma unroll
    for (int j = 0; j < 4; ++j) { STAGE_A(0, j); STAGE_B(0, j); }
    asm volatile("s_waitcnt vmcnt(0)" ::: "memory");
    __builtin_amdgcn_s_barrier();
#pragma unroll
    for (int ni = 0; ni < 4; ++ni) bv[ni] = RD(bF + ni * 2048);

#pragma unroll 1
    for (int kt = 0; kt < NT; kt += 2) {
        TILE(kt, bv, bn);
        TILE(kt + 1, bn, bv);
    }
#undef TILE
#undef MFMA_PAIR
#undef RD
#undef STAGE_A
#undef STAGE_B

    // Epilogue: e = exp(sim/TEMP) = exp2(sim * 28.8539); masked min/sum over cols.
    // C/D layout (shape-determined): col = lane&15, row = quad*4 + reg
    const float scale = 28.853900817779268f;     // 20 * log2(e)
#pragma unroll
    for (int mi = 0; mi < 8; ++mi) {
#pragma unroll
        for (int r = 0; r < 4; ++r) {
            const int row_local = wm * 128 + mi * 16 + quad * 4 + r;
            const int lab = lab_m[row_local];
            float minv = __builtin_inff();
            float sumv = 0.f;
#pragma unroll
            for (int ni = 0; ni < 4; ++ni) {
                const int col_local = wn * 64 + ni * 16 + lcol;
                const float e = exp2f(acc[mi][ni][r] * scale);
                const bool pos = (lab_n[col_local] == lab);
                minv = pos ? fminf(minv, e) : minv;
                sumv = pos ? sumv : (sumv + e);
            }
#pragma unroll
            for (int off = 1; off < 16; off <<= 1) {
                minv = fminf(minv, __shfl_xor(minv, off, 16));
                sumv += __shfl_xor(sumv, off, 16);
            }
            if (lcol == 0) {
                // partials laid out [row][part] so reduce_rows reads coalesced
                const long idx = (long)(m0 + row_local) * NPARTS + blockIdx.x * 4 + wn;
                pminp[idx] = minv;
                psump[idx] = sumv;
            }
        }
    }
}

// ---------------------------------------------------------------- row fold + mean
__global__ __launch_bounds__(256) void reduce_rows(
        const float* __restrict__ pminp, const float* __restrict__ psump,
        float* __restrict__ loss) {
    const int row  = blockIdx.x * 4 + (threadIdx.x >> 6);
    const int lane = threadIdx.x & 63;
    float m = __builtin_inff();
    float s = 0.f;
#pragma unroll
    for (int k = 0; k < NPARTS / 64; ++k) {
        const long j = (long)row * NPARTS + lane + k * 64;
        m = fminf(m, pminp[j]);
        s += psump[j];
    }
#pragma unroll
    for (int off = 1; off < 64; off <<= 1) {
        m = fminf(m, __shfl_xor(m, off, 64));
        s += __shfl_xor(s, off, 64);
    }
    if (lane == 0) loss[row] = -logf(m / (m + s + 1e-6f) + 1e-6f);
}

__global__ void final_mean(const float* __restrict__ loss, float* __restrict__ out) {
    float s = 0.f;
    for (int i = threadIdx.x; i < M_TOTAL; i += 256) s += loss[i];
#pragma unroll
    for (int off = 32; off > 0; off >>= 1) s += __shfl_xor(s, off, 64);
    __shared__ float wsum[4];
    if ((threadIdx.x & 63) == 0) wsum[threadIdx.x >> 6] = s;
    __syncthreads();
    if (threadIdx.x == 0)
        out[0] = (wsum[0] + wsum[1] + wsum[2] + wsum[3]) * (1.0f / (float)M_TOTAL);
}

// ---------------------------------------------------------------- launcher
extern "C" void kernel_launch(void* const* d_in, const int* in_sizes, int n_in,
                              void* d_out, int out_size, void* d_ws, size_t ws_size,
                              hipStream_t stream) {
    const float* feats    = (const float*)d_in[0];
    const float* feats_s  = (const float*)d_in[1];
    const int*   labels   = (const int*)d_in[2];
    const int*   labels_s = (const int*)d_in[3];
    float*       out      = (float*)d_out;

    char* ws = (char*)d_ws;
    char*  Af8   = ws;                                    //  4,194,304 B
    char*  Bf8   = ws + 4194304;                          // 33,554,432 B
    float* pminp = (float*)(ws + 37748736);               //  2,097,152 B
    float* psump = (float*)(ws + 39845888);               //  2,097,152 B
    float* loss  = (float*)(ws + 41943040);               //      8,192 B

    cvt_fp8_all<<<2560, 256, 0, stream>>>((const float4*)feats, (const float4*)feats_s,
                                          (uint4*)Af8, (uint4*)Bf8);

    dim3 grid(N_TOTAL / 256, M_TOTAL / 256);              // 64 x 8
    gemm_lp<<<grid, 512, 0, stream>>>(Af8, Bf8, labels, labels_s, pminp, psump);

    reduce_rows<<<512, 256, 0, stream>>>(pminp, psump, loss);
    final_mean<<<1, 256, 0, stream>>>(loss, out);
}

// Round 4
// 306.349 us; speedup vs baseline: 1.0901x; 1.0901x over previous
//
#include <hip/hip_runtime.h>
#include <stdint.h>

// Problem dims (fixed by setup_inputs)
#define M_TOTAL 2048     // B (feats rows)
#define N_TOTAL 16384    // Bs*TOPK (support rows)
#define K_TOTAL 2048     // C
#define NPARTS  256      // 64 n-tiles * 4 n-waves
#define NT      (K_TOTAL / 128)   // 16 K-tiles

// Uniform MX scale: stored_fp8 = value * 2^9, HW dequant scale = 2^-9 per operand.
#define SCALE_E8M0 0x76767676
#define SCALE_F 512.0f

typedef __attribute__((ext_vector_type(4))) int   int4v;    // 16B (one ds_read_b128)
typedef __attribute__((ext_vector_type(8))) int   int8v;    // 32B fp8 MFMA A/B frag
typedef __attribute__((ext_vector_type(4))) float floatx4;  // MFMA C/D frag

// ---------------------------------------------------------------- fp32 -> fp8 e4m3 (scaled)
__device__ __forceinline__ uint32_t pack8(float4 v) {
    int p = __builtin_amdgcn_cvt_pk_fp8_f32(v.x * SCALE_F, v.y * SCALE_F, 0, 0);
    p = __builtin_amdgcn_cvt_pk_fp8_f32(v.z * SCALE_F, v.w * SCALE_F, p, 1);
    return (uint32_t)p;
}

__device__ __forceinline__ void cvt_loop16(const float4* __restrict__ src,
                                           uint4* __restrict__ dst,
                                           int i, int stride, int n16) {
    for (; i < n16; i += stride) {
        const float4* p = src + (size_t)i * 4;
        uint4 o;
        o.x = pack8(p[0]);
        o.y = pack8(p[1]);
        o.z = pack8(p[2]);
        o.w = pack8(p[3]);
        dst[i] = o;
    }
}

__global__ __launch_bounds__(256) void cvt_fp8_all(
        const float4* __restrict__ a, const float4* __restrict__ b,
        uint4* __restrict__ oa, uint4* __restrict__ ob) {
    if (blockIdx.x < 512)
        cvt_loop16(a, oa, blockIdx.x * 256 + threadIdx.x, 512 * 256,
                   M_TOTAL * K_TOTAL / 16);
    else
        cvt_loop16(b, ob, (blockIdx.x - 512) * 256 + threadIdx.x, 2048 * 256,
                   N_TOTAL * K_TOTAL / 16);
}

// ---------------------------------------------------------------- GEMM + fused epilogue
__device__ __forceinline__ void load16(const void* g, void* l) {
    __builtin_amdgcn_global_load_lds(
        (const __attribute__((address_space(1))) void*)g,
        (__attribute__((address_space(3))) void*)l, 16, 0, 0);
}

__device__ __forceinline__ int8v frag8(const char* lo_p, const char* hi_p) {
    int4v lo = *(const int4v*)lo_p;
    int4v hi = *(const int4v*)hi_p;
    return (int8v){lo.x, lo.y, lo.z, lo.w, hi.x, hi.y, hi.z, hi.w};
}

// ===== 256x256 / 8 waves / dbuf LDS / FINE 4-phase counted-lgkm pipeline,
// register-streamlined after the round-3 SPILL (WRITE_SIZE 8->71 MB = scratch
// drain; VGPR pinned at the 128-arch cap beside 128 AGPR acc).
// Changes vs round 3:
//   - NO second B-frag buffer (bn): p3 interleaves {mfma row6/7(ni); re-read
//     bv[ni] from next tile's published buffer}. C++ order puts each re-read
//     after its last use -> compiler reuses the same 32 VGPRs, and can hoist
//     read ni above unrelated ni+1.. MFMAs for cover.  (-32 VGPR)
//   - Single TILE body (x2 unroll existed only for the bv/bn role swap).
// Schedule per tile (A-pairs stream one phase ahead; lgkm counts: b=oldest 8):
//   p0: stage 8 gloads (t+1, other buf); read a0..a3; BAR; lgkm(4)
//       [b(8)+a0,a1 landed; a2,a3 fly]; MFMA rows 0,1; BAR
//   p1: read a4,a5; BAR; lgkm(4) [a2,a3 landed]; MFMA rows 2,3; BAR
//   p2: read a6,a7; BAR; lgkm(4) [a4,a5 landed]; MFMA rows 4,5;
//       vmcnt(0) [stages landed, 2+ phases cover >= HBM latency]; BAR=publish
//   p3: lgkm(0) [a6,a7 landed]; per ni: {MFMA rows 6,7; bv[ni]=read next B
//       from published buf}; BAR=end [all reads of buf t retired]
// Hazards: p0 stages target buf (t+1)&1 whose last readers (tile t-1 p3)
// retired before the end BAR; p3 B-re-reads follow the publish BAR; pending
// B-reads cross the end BAR into a buffer nobody writes during t+1 p0.
__global__ __launch_bounds__(512, 2) void gemm_lp(
        const char* __restrict__ Af8, const char* __restrict__ Bf8,
        const int* __restrict__ labels, const int* __restrict__ labels_s,
        float* __restrict__ pminp, float* __restrict__ psump) {
    __shared__ __align__(16) char smA[2][256][128];   // 64 KiB
    __shared__ __align__(16) char smB[2][256][128];   // 64 KiB
    __shared__ int lab_m[256];
    __shared__ int lab_n[256];

    const int t    = threadIdx.x;
    const int lane = t & 63;
    const int wave = t >> 6;      // 0..7
    const int wm   = wave >> 2;   // row half   (0..1) -> 128 rows
    const int wn   = wave & 3;    // col quarter(0..3) -> 64 cols
    const int m0   = blockIdx.y * 256;
    const int n0   = blockIdx.x * 256;

    if (t < 256) lab_m[t] = labels[m0 + t];
    else         lab_n[t - 256] = labels_s[n0 + t - 256];

    // staging geometry: round j (0..3) covers rows j*64 + (t>>3); phys chunk t&7
    // -> global k-chunk q = (t&7) ^ ((t>>3)&7)  (row&7 is j-independent).
    const int rq = t >> 3;                                  // 0..63
    const int qt = (t & 7) ^ ((t >> 3) & 7);
    const char* aG = Af8 + (long)(m0 + rq) * K_TOTAL + qt * 16;
    const char* bG = Bf8 + (long)(n0 + rq) * K_TOTAL + qt * 16;
    const int ldst = wave * 1024;            // wave-uniform LDS base; HW adds lane*16B

#define STAGE_A(T, J) load16(aG + (T) * 128 + (J) * 64 * K_TOTAL, \
                             &smA[(T) & 1][(J) * 64][0] + ldst)
#define STAGE_B(T, J) load16(bG + (T) * 128 + (J) * 64 * K_TOTAL, \
                             &smB[(T) & 1][(J) * 64][0] + ldst)

    // Fragment bases: row R = base + lcol (+ mi*16 via 2048B immediates),
    // k-chunks {2q, 2q+1} at phys (k ^ (lcol&7)).
    const int quad = lane >> 4;
    const int lcol = lane & 15;
    const int plo = ((2 * quad)     ^ (lcol & 7)) << 4;
    const int phi = ((2 * quad + 1) ^ (lcol & 7)) << 4;
    const char* aF = &smA[0][wm * 128 + lcol][0];
    const char* bF = &smB[0][wn * 64  + lcol][0];

#define RD(P) frag8((P) + plo, (P) + phi)

    floatx4 acc[8][4];
#pragma unroll
    for (int mi = 0; mi < 8; ++mi)
#pragma unroll
        for (int ni = 0; ni < 4; ++ni)
            acc[mi][ni] = (floatx4){0.f, 0.f, 0.f, 0.f};

    int8v bv[4];

#define MFMA1(R, NI, AV)                                                       \
    acc[R][NI] = __builtin_amdgcn_mfma_scale_f32_16x16x128_f8f6f4(             \
        AV, bv[NI], acc[R][NI], 0, 0, 0, SCALE_E8M0, 0, SCALE_E8M0)

#define MFMA_PAIR(R, AV0, AV1)                                                 \
    do {                                                                       \
        _Pragma("unroll")                                                      \
        for (int ni = 0; ni < 4; ++ni) {                                       \
            MFMA1(R, ni, AV0);                                                 \
            MFMA1((R) + 1, ni, AV1);                                           \
        }                                                                      \
    } while (0)

#define TILE(KT)                                                               \
    do {                                                                       \
        const char* aB_ = aF + ((KT) & 1) * 32768;                             \
        const char* bN_ = bF + (((KT) & 1) ^ 1) * 32768;                       \
        /* ---- p0: stage next tile + read A frags 0..3 */                     \
        if ((KT) + 1 < NT) {                                                   \
            _Pragma("unroll")                                                  \
            for (int j = 0; j < 4; ++j) {                                      \
                STAGE_A((KT) + 1, j);                                          \
                STAGE_B((KT) + 1, j);                                          \
            }                                                                  \
        }                                                                      \
        int8v a0_ = RD(aB_ + 0 * 2048), a1_ = RD(aB_ + 1 * 2048);              \
        int8v a2_ = RD(aB_ + 2 * 2048), a3_ = RD(aB_ + 3 * 2048);              \
        __builtin_amdgcn_s_barrier();                                          \
        asm volatile("s_waitcnt lgkmcnt(4)" ::: "memory");                     \
        __builtin_amdgcn_sched_barrier(0);                                     \
        __builtin_amdgcn_s_setprio(1);                                         \
        MFMA_PAIR(0, a0_, a1_);                                                \
        __builtin_amdgcn_s_setprio(0);                                         \
        __builtin_amdgcn_s_barrier();                                          \
        /* ---- p1 */                                                          \
        int8v a4_ = RD(aB_ + 4 * 2048), a5_ = RD(aB_ + 5 * 2048);              \
        __builtin_amdgcn_s_barrier();                                          \
        asm volatile("s_waitcnt lgkmcnt(4)" ::: "memory");                     \
        __builtin_amdgcn_sched_barrier(0);                                     \
        __builtin_amdgcn_s_setprio(1);                                         \
        MFMA_PAIR(2, a2_, a3_);                                                \
        __builtin_amdgcn_s_setprio(0);                                         \
        __builtin_amdgcn_s_barrier();                                          \
        /* ---- p2 */                                                          \
        int8v a6_ = RD(aB_ + 6 * 2048), a7_ = RD(aB_ + 7 * 2048);              \
        __builtin_amdgcn_s_barrier();                                          \
        asm volatile("s_waitcnt lgkmcnt(4)" ::: "memory");                     \
        __builtin_amdgcn_sched_barrier(0);                                     \
        __builtin_amdgcn_s_setprio(1);                                         \
        MFMA_PAIR(4, a4_, a5_);                                                \
        __builtin_amdgcn_s_setprio(0);                                         \
        asm volatile("s_waitcnt vmcnt(0)" ::: "memory");                       \
        __builtin_amdgcn_s_barrier(); /* publish buf (KT+1)&1 */               \
        /* ---- p3: MFMA rows 6,7 interleaved with in-place B re-read */       \
        asm volatile("s_waitcnt lgkmcnt(0)" ::: "memory");                     \
        __builtin_amdgcn_sched_barrier(0);                                     \
        __builtin_amdgcn_s_setprio(1);                                         \
        _Pragma("unroll")                                                      \
        for (int ni = 0; ni < 4; ++ni) {                                       \
            MFMA1(6, ni, a6_);                                                 \
            MFMA1(7, ni, a7_);                                                 \
            bv[ni] = RD(bN_ + ni * 2048);                                      \
        }                                                                      \
        __builtin_amdgcn_s_setprio(0);                                         \
        __builtin_amdgcn_s_barrier(); /* end: all reads of buf KT&1 retired */ \
    } while (0)

    // Prologue: stage tile 0, publish, pre-read its B fragments.
#pragma unroll
    for (int j = 0; j < 4; ++j) { STAGE_A(0, j); STAGE_B(0, j); }
    asm volatile("s_waitcnt vmcnt(0)" ::: "memory");
    __builtin_amdgcn_s_barrier();
#pragma unroll
    for (int ni = 0; ni < 4; ++ni) bv[ni] = RD(bF + ni * 2048);

#pragma unroll 1
    for (int kt = 0; kt < NT; ++kt) TILE(kt);
#undef TILE
#undef MFMA_PAIR
#undef MFMA1
#undef RD
#undef STAGE_A
#undef STAGE_B

    // Epilogue: e = exp(sim/TEMP) = exp2(sim * 28.8539); masked min/sum over cols.
    // C/D layout (shape-determined): col = lane&15, row = quad*4 + reg
    const float scale = 28.853900817779268f;     // 20 * log2(e)
#pragma unroll
    for (int mi = 0; mi < 8; ++mi) {
#pragma unroll
        for (int r = 0; r < 4; ++r) {
            const int row_local = wm * 128 + mi * 16 + quad * 4 + r;
            const int lab = lab_m[row_local];
            float minv = __builtin_inff();
            float sumv = 0.f;
#pragma unroll
            for (int ni = 0; ni < 4; ++ni) {
                const int col_local = wn * 64 + ni * 16 + lcol;
                const float e = exp2f(acc[mi][ni][r] * scale);
                const bool pos = (lab_n[col_local] == lab);
                minv = pos ? fminf(minv, e) : minv;
                sumv = pos ? sumv : (sumv + e);
            }
#pragma unroll
            for (int off = 1; off < 16; off <<= 1) {
                minv = fminf(minv, __shfl_xor(minv, off, 16));
                sumv += __shfl_xor(sumv, off, 16);
            }
            if (lcol == 0) {
                // partials laid out [row][part] so reduce_rows reads coalesced
                const long idx = (long)(m0 + row_local) * NPARTS + blockIdx.x * 4 + wn;
                pminp[idx] = minv;
                psump[idx] = sumv;
            }
        }
    }
}

// ---------------------------------------------------------------- row fold + mean
__global__ __launch_bounds__(256) void reduce_rows(
        const float* __restrict__ pminp, const float* __restrict__ psump,
        float* __restrict__ loss) {
    const int row  = blockIdx.x * 4 + (threadIdx.x >> 6);
    const int lane = threadIdx.x & 63;
    float m = __builtin_inff();
    float s = 0.f;
#pragma unroll
    for (int k = 0; k < NPARTS / 64; ++k) {
        const long j = (long)row * NPARTS + lane + k * 64;
        m = fminf(m, pminp[j]);
        s += psump[j];
    }
#pragma unroll
    for (int off = 1; off < 64; off <<= 1) {
        m = fminf(m, __shfl_xor(m, off, 64));
        s += __shfl_xor(s, off, 64);
    }
    if (lane == 0) loss[row] = -logf(m / (m + s + 1e-6f) + 1e-6f);
}

__global__ void final_mean(const float* __restrict__ loss, float* __restrict__ out) {
    float s = 0.f;
    for (int i = threadIdx.x; i < M_TOTAL; i += 256) s += loss[i];
#pragma unroll
    for (int off = 32; off > 0; off >>= 1) s += __shfl_xor(s, off, 64);
    __shared__ float wsum[4];
    if ((threadIdx.x & 63) == 0) wsum[threadIdx.x >> 6] = s;
    __syncthreads();
    if (threadIdx.x == 0)
        out[0] = (wsum[0] + wsum[1] + wsum[2] + wsum[3]) * (1.0f / (float)M_TOTAL);
}

// ---------------------------------------------------------------- launcher
extern "C" void kernel_launch(void* const* d_in, const int* in_sizes, int n_in,
                              void* d_out, int out_size, void* d_ws, size_t ws_size,
                              hipStream_t stream) {
    const float* feats    = (const float*)d_in[0];
    const float* feats_s  = (const float*)d_in[1];
    const int*   labels   = (const int*)d_in[2];
    const int*   labels_s = (const int*)d_in[3];
    float*       out      = (float*)d_out;

    char* ws = (char*)d_ws;
    char*  Af8   = ws;                                    //  4,194,304 B
    char*  Bf8   = ws + 4194304;                          // 33,554,432 B
    float* pminp = (float*)(ws + 37748736);               //  2,097,152 B
    float* psump = (float*)(ws + 39845888);               //  2,097,152 B
    float* loss  = (float*)(ws + 41943040);               //      8,192 B

    cvt_fp8_all<<<2560, 256, 0, stream>>>((const float4*)feats, (const float4*)feats_s,
                                          (uint4*)Af8, (uint4*)Bf8);

    dim3 grid(N_TOTAL / 256, M_TOTAL / 256);              // 64 x 8
    gemm_lp<<<grid, 512, 0, stream>>>(Af8, Bf8, labels, labels_s, pminp, psump);

    reduce_rows<<<512, 256, 0, stream>>>(pminp, psump, loss);
    final_mean<<<1, 256, 0, stream>>>(loss, out);
}